// Round 9
// baseline (316.430 us; speedup 1.0000x reference)
//
#include <hip/hip_runtime.h>
#include <hip/hip_cooperative_groups.h>
#include <stdint.h>

namespace cg = cooperative_groups;

#define NB 32
#define NN 2048
#define NR 100
#define NW 64       // u32 words per suppression row
#define ROWCAP 256  // precomputed suppression rows (walk has exact fallback past this)
#define TPB 244     // valid wave-tiles per batch (ct >= 2*rt)
#define NTILES (NB * TPB)   // 7808
#define NWAVES 4096         // 256 blocks * 16 waves

__device__ __forceinline__ uint32_t ordered_f32(float f) {
    uint32_t u = __float_as_uint(f);
    return (u & 0x80000000u) ? ~u : (u | 0x80000000u);
}

// ---------------------------------------------------------------------------
// One cooperative kernel, three phases separated by grid.sync():
//  R: rank-by-counting stable sort (exact argsort(-scores) permutation);
//     emits sortedBox[b][rank] and cHalf[b][rank] = 0.5f*area.
//  P: suppression bit matrix, rows < ROWCAP, upper triangle; wave-tile =
//     64 rows x 32 cols, flat tile list (ct >= 2*rt), <=2 tiles/wave.
//     Exact ref semantics: RN(inter/aj) >= 0.5 <=> inter >= 0.5f*aj (the
//     true threshold c - c*2^-25 lies in (pred(c), c); no f32 exists there).
//  W: serial greedy walk, wave 0 of blocks 0..31; early exit at 100 kept;
//     exact on-the-fly fallback past ROWCAP (pathological inputs only).
// ---------------------------------------------------------------------------
__global__ __launch_bounds__(1024) void nms_fused(const float* __restrict__ pred,
                                                  float4* __restrict__ sortedBox,
                                                  float* __restrict__ cHalf,
                                                  uint32_t* __restrict__ M,
                                                  float* __restrict__ out) {
    __shared__ uint64_t keys[NN];          // 16 KB (phase R)
    __shared__ int      psum[16][256];     // 16 KB (phase R)
    __shared__ int      slots[NR];         // phase W
    __shared__ int      s_count;           // phase W

    cg::grid_group grid = cg::this_grid();
    const int tid  = threadIdx.x;
    const int wv   = tid >> 6;
    const int lane = tid & 63;

    // ---------------- Phase R: rank ----------------
    {
        const int b   = blockIdx.x >> 3;   // batch
        const int blk = blockIdx.x & 7;    // chunk of 256 rows
        const float* p = pred + (size_t)b * NN * 5;

        for (int i = tid; i < NN; i += 1024) {
            float sc = p[i * 5 + 0];
            keys[i] = ((uint64_t)(~ordered_f32(sc)) << 32) | (uint32_t)i;
        }
        __syncthreads();

        uint64_t myk[4];
        int      cnt[4] = {0, 0, 0, 0};
#pragma unroll
        for (int r = 0; r < 4; ++r)
            myk[r] = keys[blk * 256 + lane + 64 * r];

        const ulonglong2* k2 = (const ulonglong2*)keys + wv * 64; // cols [wv*128,+128)
#pragma unroll 8
        for (int jj = 0; jj < 64; ++jj) {  // wave-uniform broadcast, 1 DS / 16 VALU
            ulonglong2 kk = k2[jj];
#pragma unroll
            for (int r = 0; r < 4; ++r)
                cnt[r] += (kk.x < myk[r]) + (kk.y < myk[r]);
        }
#pragma unroll
        for (int r = 0; r < 4; ++r)
            psum[wv][lane + 64 * r] = cnt[r];
        __syncthreads();

        if (tid < 256) {
            int rank = 0;
#pragma unroll
            for (int s = 0; s < 16; ++s) rank += psum[s][tid];
            const float* q = p + (size_t)(blk * 256 + tid) * 5;
            float l = q[1], t = q[2], r = q[3], d = q[4];
            sortedBox[(size_t)b * NN + rank] = make_float4(l, t, r, d);
            cHalf[(size_t)b * NN + rank]    = 0.5f * ((r - l) * (d - t));
        }
    }
    __threadfence();
    grid.sync();

    // ---------------- Phase P: pairs ----------------
    {
        const int w = blockIdx.x * 16 + wv;
        for (int t = w; t < NTILES; t += NWAVES) {
            const uint32_t bb = (uint32_t)t / TPB;   // batch (wave-uniform)
            const int lt = t - (int)bb * TPB;
            int rt, ct;
            if      (lt <  64) { rt = 0; ct = lt;       }
            else if (lt < 126) { rt = 1; ct = lt - 62;  }
            else if (lt < 186) { rt = 2; ct = lt - 122; }
            else               { rt = 3; ct = lt - 180; }

            const float4* box = sortedBox + (size_t)bb * NN;
            const int i = rt * 64 + lane;            // this lane's row
            const float4 bi = box[i];                // coalesced per-lane load
            const float4* cb = box + ct * 32;        // wave-uniform -> scalar path
            const float*  ch = cHalf + (size_t)bb * NN + ct * 32;

            uint32_t roww = 0;
#pragma unroll
            for (int k = 0; k < 32; ++k) {
                float4 c4 = cb[k];
                float  c  = ch[k];
                float il = fmaxf(bi.x, c4.x);
                float iy = fmaxf(bi.y, c4.y);
                float ir = fminf(bi.z, c4.z);
                float ib = fminf(bi.w, c4.w);
                float inter = fmaxf(ir - il, 0.0f) * fmaxf(ib - iy, 0.0f);
                roww |= (inter >= c) ? (1u << k) : 0u;   // bit k = col 32ct+k
            }
            const int d = i - ct * 32;               // mask cols j <= i
            uint32_t um = (d < 0) ? 0xFFFFFFFFu
                                  : ((d >= 31) ? 0u : (0xFFFFFFFFu << (d + 1)));
            M[((size_t)bb * ROWCAP + i) * NW + ct] = roww & um;
        }
    }
    __threadfence();
    grid.sync();

    // ---------------- Phase W: walk ----------------
    if (blockIdx.x < NB) {
        const int b = blockIdx.x;
        const uint32_t* Mb = M + (size_t)b * ROWCAP * NW;
        const float4* box  = sortedBox + (size_t)b * NN;

        if (wv == 0) {
            uint32_t keep = 0xFFFFFFFFu;
            int count = 0;

            for (int i0 = 0; i0 < ROWCAP; i0 += 8) {
                uint32_t rr[8];
#pragma unroll
                for (int k = 0; k < 8; ++k)        // 8 independent loads in flight
                    rr[k] = Mb[(size_t)(i0 + k) * NW + lane];
#pragma unroll
                for (int k = 0; k < 8; ++k) {
                    const int i = i0 + k;
                    uint32_t kw = __shfl(keep, i >> 5);
                    if ((kw >> (i & 31)) & 1u) {   // box i survives -> suppress row
                        uint32_t vm = ((lane >> 1) >= (i >> 6)) ? rr[k] : 0u;
                        keep &= ~vm;
                        if (lane == 0 && count < NR) slots[count] = i;
                        ++count;
                    }
                }
                if (count >= NR) break;            // first 100 kept are final
            }

            // Fallback (correctness only; not expected for this input).
            if (count < NR) {
                for (int i = ROWCAP; i < NN && count < NR; ++i) {
                    uint32_t kw = __shfl(keep, i >> 5);
                    if ((kw >> (i & 31)) & 1u) {
                        float4 bi = box[i];
                        uint32_t kill = 0;
                        for (int tt = 0; tt < 32; ++tt) {
                            int j = lane * 32 + tt;
                            if (j > i) {
                                float4 bj = box[j];
                                float c  = 0.5f * ((bj.z - bj.x) * (bj.w - bj.y));
                                float il = fmaxf(bi.x, bj.x);
                                float iy = fmaxf(bi.y, bj.y);
                                float ir = fminf(bi.z, bj.z);
                                float ib = fminf(bi.w, bj.w);
                                float inter = fmaxf(ir - il, 0.0f) * fmaxf(ib - iy, 0.0f);
                                if (inter >= c) kill |= (1u << tt);
                            }
                        }
                        keep &= ~kill;
                        if (lane == 0 && count < NR) slots[count] = i;
                        ++count;
                    }
                }
            }
            if (lane == 0) s_count = count;
        }
        __syncthreads();

        const int count = s_count;
        for (int s = tid; s < NR; s += 1024) {
            float x = 0.f, y = 0.f, z = 0.f;
            if (s < count) {
                float4 q = box[slots[s]];
                x = q.y; y = q.z; z = q.w;         // vals = (top, right, bottom)
            }
            float* o = out + ((size_t)b * NR + s) * 3;
            o[0] = x; o[1] = y; o[2] = z;
        }
    }
}

// ---------------------------------------------------------------------------
extern "C" void kernel_launch(void* const* d_in, const int* in_sizes, int n_in,
                              void* d_out, int out_size, void* d_ws, size_t ws_size,
                              hipStream_t stream) {
    const float* pred = (const float*)d_in[0];
    float* out = (float*)d_out;
    char* ws = (char*)d_ws;

    float4*   sortedBox = (float4*)ws;                               // 1 MB
    uint32_t* M         = (uint32_t*)(ws + (size_t)(1 << 20));       // 2 MB
    float*    cHalf     = (float*)(ws + (size_t)(3 << 20));          // 256 KB

    void* args[] = { (void*)&pred, (void*)&sortedBox, (void*)&cHalf,
                     (void*)&M, (void*)&out };
    hipLaunchCooperativeKernel(reinterpret_cast<void*>(nms_fused),
                               dim3(256), dim3(1024), args, 0, stream);
}

// Round 10
// 121.868 us; speedup vs baseline: 2.5965x; 2.5965x over previous
//
#include <hip/hip_runtime.h>
#include <hip/hip_cooperative_groups.h>
#include <stdint.h>

#define NB 32
#define NN 2048
#define NR 100
#define MROW 128           // precomputed suppression rows (walk has exact fallback past this)
#define MCT 64             // u32 col-words per row (2048 cols)
#define MAGIC 0x5A17ED01u

__device__ __forceinline__ uint32_t ordered_f32(float f) {
    uint32_t u = __float_as_uint(f);
    return (u & 0x80000000u) ? ~u : (u | 0x80000000u);
}

// ---------------------------------------------------------------------------
// Single cooperative kernel, per-batch flag barriers (NO grid.sync).
// Grid 256 blocks x 1024 thr; block g = (batch b = g>>3, chunk c = g&7).
//  R: rank-by-counting stable sort (exact argsort(-scores) permutation);
//     chunk c ranks rows [256c, 256c+256) of batch b.
//  barrier1(b): 8 release-flags + acquire-spin (wbl2/inv via atomics).
//  P: suppression bits, rows < MROW, upper triangle. 126 wave-tiles
//     (64 rows x 32 cols) over the batch's 8 blocks x 16 waves = 1 tile/wave.
//     Cols + thresholds staged in LDS (vector loads, post-inv -> coherent).
//     Exact ref semantics: RN(inter/aj) >= 0.5 <=> inter >= 0.5f*aj (the true
//     threshold c - c*2^-25 lies in (pred(c), c); no f32 exists there).
//     M transposed: M[b][ct][row] -> coalesced stores.
//  barrier2(b): blocks signal; block (b,0) acquires, resets flags to 0
//     (replay-safe), walks, writes output.
// ---------------------------------------------------------------------------
__global__ __launch_bounds__(1024) void nms_one(const float* __restrict__ pred,
                                                float4* __restrict__ sortedBox,
                                                float* __restrict__ cHalf,
                                                uint32_t* __restrict__ M,
                                                uint32_t* flags,   // [2][NB][8]
                                                float* __restrict__ out) {
    __shared__ union {
        struct { uint64_t keys[NN]; int psum[16][256]; } r;   // 32 KB
        struct { float4 col[NN]; float ch[NN]; } p;           // 40 KB
    } sm;
    __shared__ int slots[NR];
    __shared__ int s_count;

    const int b    = blockIdx.x >> 3;
    const int c    = blockIdx.x & 7;
    const int tid  = threadIdx.x;
    const int wv   = tid >> 6;
    const int lane = tid & 63;
    const float* p = pred + (size_t)b * NN * 5;

    // ---------------- Phase R: rank ----------------
    for (int i = tid; i < NN; i += 1024) {
        float sc = p[i * 5 + 0];
        sm.r.keys[i] = ((uint64_t)(~ordered_f32(sc)) << 32) | (uint32_t)i;
    }
    __syncthreads();

    uint64_t myk[4];
    int      cnt[4] = {0, 0, 0, 0};
#pragma unroll
    for (int r = 0; r < 4; ++r)
        myk[r] = sm.r.keys[c * 256 + lane + 64 * r];

    const ulonglong2* k2 = (const ulonglong2*)sm.r.keys + wv * 64;
#pragma unroll 8
    for (int jj = 0; jj < 64; ++jj) {      // wave-uniform broadcast, 1 DS / 16 VALU
        ulonglong2 kk = k2[jj];
#pragma unroll
        for (int r = 0; r < 4; ++r)
            cnt[r] += (kk.x < myk[r]) + (kk.y < myk[r]);
    }
#pragma unroll
    for (int r = 0; r < 4; ++r)
        sm.r.psum[wv][lane + 64 * r] = cnt[r];
    __syncthreads();

    if (tid < 256) {
        int rank = 0;
#pragma unroll
        for (int s = 0; s < 16; ++s) rank += sm.r.psum[s][tid];
        const float* q = p + (size_t)(c * 256 + tid) * 5;
        float bl = q[1], bt = q[2], br = q[3], bb = q[4];
        sortedBox[(size_t)b * NN + rank] = make_float4(bl, bt, br, bb);
        cHalf[(size_t)b * NN + rank]    = 0.5f * ((br - bl) * (bb - bt));
    }

    // ---------------- barrier 1 (batch-wide) ----------------
    __syncthreads();                        // all waves drain their stores
    if (tid == 0)
        __hip_atomic_store(&flags[b * 8 + c], MAGIC,
                           __ATOMIC_RELEASE, __HIP_MEMORY_SCOPE_AGENT);
    if (tid < 8)
        while (__hip_atomic_load(&flags[b * 8 + tid],
                                 __ATOMIC_ACQUIRE, __HIP_MEMORY_SCOPE_AGENT) != MAGIC)
            __builtin_amdgcn_s_sleep(2);
    __syncthreads();                        // inv done before any wave's loads

    // ---------------- Phase P: pairs ----------------
    const float4* box = sortedBox + (size_t)b * NN;
    for (int j = tid; j < NN; j += 1024) {  // stage cols (vector loads, coherent)
        sm.p.col[j] = box[j];
        sm.p.ch[j]  = cHalf[(size_t)b * NN + j];
    }
    __syncthreads();

    const int widx = c * 16 + wv;           // 0..127, 126 valid tiles
    if (widx < 126) {
        const int rt = (widx < 64) ? 0 : 1;
        const int ct = (widx < 64) ? widx : widx - 62;
        const int i  = rt * 64 + lane;      // this lane's row
        const float4 bi = sm.p.col[i];

        uint32_t roww = 0;
        const int jb = ct * 32;
#pragma unroll
        for (int k = 0; k < 32; ++k) {
            float4 cb = sm.p.col[jb + k];   // wave-uniform broadcast
            float  cc = sm.p.ch[jb + k];
            float il = fmaxf(bi.x, cb.x);
            float iy = fmaxf(bi.y, cb.y);
            float ir = fminf(bi.z, cb.z);
            float ib = fminf(bi.w, cb.w);
            float inter = fmaxf(ir - il, 0.0f) * fmaxf(ib - iy, 0.0f);
            roww |= (inter >= cc) ? (1u << k) : 0u;   // bit k = col 32ct+k
        }
        const int d = i - jb;               // mask cols j <= i
        uint32_t um = (d < 0) ? 0xFFFFFFFFu
                              : ((d >= 31) ? 0u : (0xFFFFFFFFu << (d + 1)));
        M[(size_t)b * MCT * MROW + (size_t)ct * MROW + i] = roww & um;
    }

    // ---------------- barrier 2 + walk (block (b,0) only) ----------------
    __syncthreads();                        // drain M stores
    if (tid == 0)
        __hip_atomic_store(&flags[(NB + b) * 8 + c], MAGIC,
                           __ATOMIC_RELEASE, __HIP_MEMORY_SCOPE_AGENT);
    if (c != 0) return;

    if (tid < 8)
        while (__hip_atomic_load(&flags[(NB + b) * 8 + tid],
                                 __ATOMIC_ACQUIRE, __HIP_MEMORY_SCOPE_AGENT) != MAGIC)
            __builtin_amdgcn_s_sleep(2);
    __syncthreads();
    if (tid < 8) {                          // reset flags for next replay
        __hip_atomic_store(&flags[b * 8 + tid], 0u,
                           __ATOMIC_RELAXED, __HIP_MEMORY_SCOPE_AGENT);
        __hip_atomic_store(&flags[(NB + b) * 8 + tid], 0u,
                           __ATOMIC_RELAXED, __HIP_MEMORY_SCOPE_AGENT);
    }

    if (wv == 0) {
        const uint32_t* Mt = M + (size_t)b * MCT * MROW;   // [ct][row]
        uint32_t keep = 0xFFFFFFFFu;
        int count = 0;

        for (int i0 = 0; i0 < MROW; i0 += 8) {
            uint32_t rr[8];
#pragma unroll
            for (int k = 0; k < 8; ++k)     // 8 independent loads in flight
                rr[k] = Mt[(size_t)lane * MROW + i0 + k];
#pragma unroll
            for (int k = 0; k < 8; ++k) {
                const int i = i0 + k;
                uint32_t kw = __shfl(keep, i >> 5);
                if ((kw >> (i & 31)) & 1u) {           // box i survives
                    uint32_t vm = ((lane >> 1) >= (i >> 6)) ? rr[k] : 0u;
                    keep &= ~vm;
                    if (lane == 0 && count < NR) slots[count] = i;
                    ++count;
                }
            }
            if (count >= NR) break;         // first 100 kept are final
        }

        // Fallback (correctness only; not expected for this input).
        if (count < NR) {
            for (int i = MROW; i < NN && count < NR; ++i) {
                uint32_t kw = __shfl(keep, i >> 5);
                if ((kw >> (i & 31)) & 1u) {
                    const volatile float* vb = (const volatile float*)(box + i);
                    float bx = vb[0], by = vb[1], bz = vb[2], bw = vb[3];
                    uint32_t kill = 0;
                    for (int t = 0; t < 32; ++t) {
                        int j = lane * 32 + t;
                        if (j > i) {
                            const volatile float* vj = (const volatile float*)(box + j);
                            float jx = vj[0], jy = vj[1], jz = vj[2], jw = vj[3];
                            float cc = 0.5f * ((jz - jx) * (jw - jy));
                            float il = fmaxf(bx, jx);
                            float iy = fmaxf(by, jy);
                            float ir = fminf(bz, jz);
                            float ib = fminf(bw, jw);
                            float inter = fmaxf(ir - il, 0.0f) * fmaxf(ib - iy, 0.0f);
                            if (inter >= cc) kill |= (1u << t);
                        }
                    }
                    keep &= ~kill;
                    if (lane == 0 && count < NR) slots[count] = i;
                    ++count;
                }
            }
        }
        if (lane == 0) s_count = count;
    }
    __syncthreads();

    const int count = s_count;
    for (int s = tid; s < NR; s += 1024) {
        float x = 0.f, y = 0.f, z = 0.f;
        if (s < count) {
            float4 q = box[slots[s]];
            x = q.y; y = q.z; z = q.w;      // vals = (top, right, bottom)
        }
        float* o = out + ((size_t)b * NR + s) * 3;
        o[0] = x; o[1] = y; o[2] = z;
    }
}

// ---------------------------------------------------------------------------
extern "C" void kernel_launch(void* const* d_in, const int* in_sizes, int n_in,
                              void* d_out, int out_size, void* d_ws, size_t ws_size,
                              hipStream_t stream) {
    const float* pred = (const float*)d_in[0];
    float* out = (float*)d_out;
    char* ws = (char*)d_ws;

    float4*   sortedBox = (float4*)ws;                              // 1 MB @ 0
    float*    cHalf     = (float*)(ws + (size_t)(1 << 20));         // 256 KB
    uint32_t* M         = (uint32_t*)(ws + (size_t)(1 << 20) + (256 << 10)); // 1 MB
    uint32_t* flags     = (uint32_t*)(ws + (size_t)(3 << 20));      // 2 KB

    void* args[] = { (void*)&pred, (void*)&sortedBox, (void*)&cHalf,
                     (void*)&M, (void*)&flags, (void*)&out };
    hipLaunchCooperativeKernel(reinterpret_cast<void*>(nms_one),
                               dim3(256), dim3(1024), args, 0, stream);
}

// Round 11
// 120.411 us; speedup vs baseline: 2.6279x; 1.0121x over previous
//
#include <hip/hip_runtime.h>
#include <hip/hip_cooperative_groups.h>
#include <stdint.h>

#define NB 32
#define NN 2048
#define NR 100
#define MROW 128           // precomputed suppression rows (walk has exact fallback past this)
#define MCT 64             // u32 col-words per row (2048 cols)
#define MAGIC 0x5A17ED01u

__device__ __forceinline__ uint32_t ordered_f32(float f) {
    uint32_t u = __float_as_uint(f);
    return (u & 0x80000000u) ? ~u : (u | 0x80000000u);
}

// ---------------------------------------------------------------------------
// Single cooperative kernel, per-batch flag barriers (NO grid.sync).
// Grid 256 blocks x 1024 thr; block g = (batch b = g>>3, chunk c = g&7).
//  R: rank-by-counting stable sort (exact argsort(-scores) permutation).
//  barrier1(b): producer = __syncthreads (stores drained per-wave) +
//     ONE fence(RELEASE, agent) (single buffer_wbl2) + RELAXED flag store;
//     consumer = RELAXED spin (agent atomics hit the coherent point, no
//     cache-maintenance per poll) + ONE fence(ACQUIRE, agent) + barrier.
//     (Round-10's ACQUIRE-polling emitted buffer_inv per poll -> L2 thrash,
//      8x HBM over-fetch, 101 us. This drops cache ops to 2 per block.)
//  P: suppression bits, rows < MROW, upper triangle. 126 wave-tiles
//     (64 rows x 32 cols); cols + thresholds staged in LDS.
//     Exact ref semantics: RN(inter/aj) >= 0.5 <=> inter >= 0.5f*aj (the true
//     threshold c - c*2^-25 lies in (pred(c), c); no f32 exists there).
//     M transposed: M[b][ct][row] -> coalesced stores.
//  barrier2(b): same protocol; block (b,0) then resets flags (replay-safe)
//     and walks; early exit at 100 kept; exact fallback past MROW.
// ---------------------------------------------------------------------------
__global__ __launch_bounds__(1024) void nms_one(const float* __restrict__ pred,
                                                float4* __restrict__ sortedBox,
                                                float* __restrict__ cHalf,
                                                uint32_t* __restrict__ M,
                                                uint32_t* flags,   // [2][NB][8]
                                                float* __restrict__ out) {
    __shared__ union {
        struct { uint64_t keys[NN]; int psum[16][256]; } r;   // 32 KB
        struct { float4 col[NN]; float ch[NN]; } p;           // 40 KB
    } sm;
    __shared__ int slots[NR];
    __shared__ int s_count;

    const int b    = blockIdx.x >> 3;
    const int c    = blockIdx.x & 7;
    const int tid  = threadIdx.x;
    const int wv   = tid >> 6;
    const int lane = tid & 63;
    const float* p = pred + (size_t)b * NN * 5;

    // ---------------- Phase R: rank ----------------
    for (int i = tid; i < NN; i += 1024) {
        float sc = p[i * 5 + 0];
        sm.r.keys[i] = ((uint64_t)(~ordered_f32(sc)) << 32) | (uint32_t)i;
    }
    __syncthreads();

    uint64_t myk[4];
    int      cnt[4] = {0, 0, 0, 0};
#pragma unroll
    for (int r = 0; r < 4; ++r)
        myk[r] = sm.r.keys[c * 256 + lane + 64 * r];

    const ulonglong2* k2 = (const ulonglong2*)sm.r.keys + wv * 64;
#pragma unroll 8
    for (int jj = 0; jj < 64; ++jj) {      // wave-uniform broadcast, 1 DS / 16 VALU
        ulonglong2 kk = k2[jj];
#pragma unroll
        for (int r = 0; r < 4; ++r)
            cnt[r] += (kk.x < myk[r]) + (kk.y < myk[r]);
    }
#pragma unroll
    for (int r = 0; r < 4; ++r)
        sm.r.psum[wv][lane + 64 * r] = cnt[r];
    __syncthreads();

    if (tid < 256) {
        int rank = 0;
#pragma unroll
        for (int s = 0; s < 16; ++s) rank += sm.r.psum[s][tid];
        const float* q = p + (size_t)(c * 256 + tid) * 5;
        float bl = q[1], bt = q[2], br = q[3], bb = q[4];
        sortedBox[(size_t)b * NN + rank] = make_float4(bl, bt, br, bb);
        cHalf[(size_t)b * NN + rank]    = 0.5f * ((br - bl) * (bb - bt));
    }

    // ---------------- barrier 1 (batch-wide, cheap) ----------------
    __syncthreads();                        // every wave's stores drained to L2
    if (tid == 0) {
        __builtin_amdgcn_fence(__ATOMIC_RELEASE, "agent");   // one wbl2
        __hip_atomic_store(&flags[b * 8 + c], MAGIC,
                           __ATOMIC_RELAXED, __HIP_MEMORY_SCOPE_AGENT);
    }
    if (tid < 8) {
        while (__hip_atomic_load(&flags[b * 8 + tid],
                                 __ATOMIC_RELAXED, __HIP_MEMORY_SCOPE_AGENT) != MAGIC)
            __builtin_amdgcn_s_sleep(2);
    }
    if (tid == 0)
        __builtin_amdgcn_fence(__ATOMIC_ACQUIRE, "agent");   // one inv
    __syncthreads();                        // inv done before any wave's loads

    // ---------------- Phase P: pairs ----------------
    const float4* box = sortedBox + (size_t)b * NN;
    for (int j = tid; j < NN; j += 1024) {  // stage cols (post-inv -> coherent)
        sm.p.col[j] = box[j];
        sm.p.ch[j]  = cHalf[(size_t)b * NN + j];
    }
    __syncthreads();

    const int widx = c * 16 + wv;           // 0..127, 126 valid tiles
    if (widx < 126) {
        const int rt = (widx < 64) ? 0 : 1;
        const int ct = (widx < 64) ? widx : widx - 62;
        const int i  = rt * 64 + lane;      // this lane's row
        const float4 bi = sm.p.col[i];

        uint32_t roww = 0;
        const int jb = ct * 32;
#pragma unroll
        for (int k = 0; k < 32; ++k) {
            float4 cb = sm.p.col[jb + k];   // wave-uniform broadcast
            float  cc = sm.p.ch[jb + k];
            float il = fmaxf(bi.x, cb.x);
            float iy = fmaxf(bi.y, cb.y);
            float ir = fminf(bi.z, cb.z);
            float ib = fminf(bi.w, cb.w);
            float inter = fmaxf(ir - il, 0.0f) * fmaxf(ib - iy, 0.0f);
            roww |= (inter >= cc) ? (1u << k) : 0u;   // bit k = col 32ct+k
        }
        const int d = i - jb;               // mask cols j <= i
        uint32_t um = (d < 0) ? 0xFFFFFFFFu
                              : ((d >= 31) ? 0u : (0xFFFFFFFFu << (d + 1)));
        M[(size_t)b * MCT * MROW + (size_t)ct * MROW + i] = roww & um;
    }

    // ---------------- barrier 2 + walk (block (b,0) only) ----------------
    __syncthreads();                        // drain M stores
    if (tid == 0) {
        __builtin_amdgcn_fence(__ATOMIC_RELEASE, "agent");
        __hip_atomic_store(&flags[(NB + b) * 8 + c], MAGIC,
                           __ATOMIC_RELAXED, __HIP_MEMORY_SCOPE_AGENT);
    }
    if (c != 0) return;

    if (tid < 8) {
        while (__hip_atomic_load(&flags[(NB + b) * 8 + tid],
                                 __ATOMIC_RELAXED, __HIP_MEMORY_SCOPE_AGENT) != MAGIC)
            __builtin_amdgcn_s_sleep(2);
    }
    if (tid == 0)
        __builtin_amdgcn_fence(__ATOMIC_ACQUIRE, "agent");
    __syncthreads();
    if (tid < 8) {                          // reset flags for next replay
        __hip_atomic_store(&flags[b * 8 + tid], 0u,
                           __ATOMIC_RELAXED, __HIP_MEMORY_SCOPE_AGENT);
        __hip_atomic_store(&flags[(NB + b) * 8 + tid], 0u,
                           __ATOMIC_RELAXED, __HIP_MEMORY_SCOPE_AGENT);
    }

    if (wv == 0) {
        const uint32_t* Mt = M + (size_t)b * MCT * MROW;   // [ct][row]
        uint32_t keep = 0xFFFFFFFFu;
        int count = 0;

        for (int i0 = 0; i0 < MROW; i0 += 8) {
            uint32_t rr[8];
#pragma unroll
            for (int k = 0; k < 8; ++k)     // 8 independent loads in flight
                rr[k] = Mt[(size_t)lane * MROW + i0 + k];
#pragma unroll
            for (int k = 0; k < 8; ++k) {
                const int i = i0 + k;
                uint32_t kw = __shfl(keep, i >> 5);
                if ((kw >> (i & 31)) & 1u) {           // box i survives
                    uint32_t vm = ((lane >> 1) >= (i >> 6)) ? rr[k] : 0u;
                    keep &= ~vm;
                    if (lane == 0 && count < NR) slots[count] = i;
                    ++count;
                }
            }
            if (count >= NR) break;         // first 100 kept are final
        }

        // Fallback (correctness only; not expected for this input).
        if (count < NR) {
            for (int i = MROW; i < NN && count < NR; ++i) {
                uint32_t kw = __shfl(keep, i >> 5);
                if ((kw >> (i & 31)) & 1u) {
                    const volatile float* vb = (const volatile float*)(box + i);
                    float bx = vb[0], by = vb[1], bz = vb[2], bw = vb[3];
                    uint32_t kill = 0;
                    for (int t = 0; t < 32; ++t) {
                        int j = lane * 32 + t;
                        if (j > i) {
                            const volatile float* vj = (const volatile float*)(box + j);
                            float jx = vj[0], jy = vj[1], jz = vj[2], jw = vj[3];
                            float cc = 0.5f * ((jz - jx) * (jw - jy));
                            float il = fmaxf(bx, jx);
                            float iy = fmaxf(by, jy);
                            float ir = fminf(bz, jz);
                            float ib = fminf(bw, jw);
                            float inter = fmaxf(ir - il, 0.0f) * fmaxf(ib - iy, 0.0f);
                            if (inter >= cc) kill |= (1u << t);
                        }
                    }
                    keep &= ~kill;
                    if (lane == 0 && count < NR) slots[count] = i;
                    ++count;
                }
            }
        }
        if (lane == 0) s_count = count;
    }
    __syncthreads();

    const int count = s_count;
    for (int s = tid; s < NR; s += 1024) {
        float x = 0.f, y = 0.f, z = 0.f;
        if (s < count) {
            float4 q = box[slots[s]];
            x = q.y; y = q.z; z = q.w;      // vals = (top, right, bottom)
        }
        float* o = out + ((size_t)b * NR + s) * 3;
        o[0] = x; o[1] = y; o[2] = z;
    }
}

// ---------------------------------------------------------------------------
extern "C" void kernel_launch(void* const* d_in, const int* in_sizes, int n_in,
                              void* d_out, int out_size, void* d_ws, size_t ws_size,
                              hipStream_t stream) {
    const float* pred = (const float*)d_in[0];
    float* out = (float*)d_out;
    char* ws = (char*)d_ws;

    float4*   sortedBox = (float4*)ws;                              // 1 MB @ 0
    float*    cHalf     = (float*)(ws + (size_t)(1 << 20));         // 256 KB
    uint32_t* M         = (uint32_t*)(ws + (size_t)(1 << 20) + (256 << 10)); // 1 MB
    uint32_t* flags     = (uint32_t*)(ws + (size_t)(3 << 20));      // 2 KB

    void* args[] = { (void*)&pred, (void*)&sortedBox, (void*)&cHalf,
                     (void*)&M, (void*)&flags, (void*)&out };
    hipLaunchCooperativeKernel(reinterpret_cast<void*>(nms_one),
                               dim3(256), dim3(1024), args, 0, stream);
}